// Round 6
// baseline (232.644 us; speedup 1.0000x reference)
//
#include <hip/hip_runtime.h>
#include <stdint.h>

#define DIM 256
#define NR 8192
#define BM 128
#define BN 128
#define BK 64
#define TPB 8           // tiles per block
#define GRID 512        // 64 bx * 8 bb
#define REP 3           // diagnostic: repeat tile loop (idempotent rewrites) so the
                        // gemm dispatch outlasts the harness fills and surfaces in rocprof

typedef __bf16 bf16x8 __attribute__((ext_vector_type(8)));
typedef float  f32x16 __attribute__((ext_vector_type(16)));
typedef float  f32x4  __attribute__((ext_vector_type(4)));

#define MEMFENCE asm volatile("" ::: "memory")
#define WAITV(N) asm volatile("s_waitcnt vmcnt(" #N ")" ::: "memory")
#define BAR __builtin_amdgcn_s_barrier()

__device__ __forceinline__ unsigned short f2bf_rne(float f) {
    unsigned int u = __float_as_uint(f);
    u += 0x7FFFu + ((u >> 16) & 1u);
    return (unsigned short)(u >> 16);
}

// One wave per row: f32 row -> bf16 + ||row||^2. Blocks [0,2048)->a, rest->b.
__global__ void prep_kernel(const float* __restrict__ a,
                            const float* __restrict__ b,
                            unsigned short* __restrict__ aB,
                            unsigned short* __restrict__ bB,
                            float* __restrict__ na,
                            float* __restrict__ nb) {
    const int w = threadIdx.x >> 6;
    const int l = threadIdx.x & 63;
    const int blk = blockIdx.x;
    const float* src; unsigned short* dst; float* nrm; int row;
    if (blk < 2048) { src = a; dst = aB; nrm = na; row = blk * 4 + w; }
    else            { src = b; dst = bB; nrm = nb; row = (blk - 2048) * 4 + w; }
    const float4 v = reinterpret_cast<const float4*>(src + (size_t)row * DIM)[l];
    float ss = v.x * v.x + v.y * v.y + v.z * v.z + v.w * v.w;
#pragma unroll
    for (int off = 32; off > 0; off >>= 1) ss += __shfl_down(ss, off);
    if (l == 0) nrm[row] = ss;
    ushort4 o = make_ushort4(f2bf_rne(v.x), f2bf_rne(v.y), f2bf_rne(v.z), f2bf_rne(v.w));
    reinterpret_cast<ushort4*>(dst + (size_t)row * DIM)[l] = o;
}

// Swizzled staging: LDS granule G=(rp*16+pos) holds global granule
// (r = 2*rp + (c2>>3), c = c2&7) with c2 = pos ^ (rp&15).  Inverse of the
// read mapping byte = ((r>>1)*16 + (((r&1)*8 + c) ^ ((r>>1)&15))) * 16.
#define STAGE(row0_, kt_, buf_)                                                   \
    do {                                                                          \
        _Pragma("unroll")                                                         \
        for (int it_ = 0; it_ < 4; ++it_) {                                       \
            __builtin_amdgcn_global_load_lds(                                     \
                (const __attribute__((address_space(1))) void*)(aB +              \
                    (size_t)((row0_) + rowIt[it_]) * DIM + (kt_) * BK + colIt[it_]), \
                (__attribute__((address_space(3))) void*)&sA[buf_][(w * 4 + it_) * 512], \
                16, 0, 0);                                                        \
        }                                                                         \
        _Pragma("unroll")                                                         \
        for (int it_ = 0; it_ < 4; ++it_) {                                       \
            __builtin_amdgcn_global_load_lds(                                     \
                (const __attribute__((address_space(1))) void*)(bB +              \
                    (size_t)(col0 + rowIt[it_]) * DIM + (kt_) * BK + colIt[it_]), \
                (__attribute__((address_space(3))) void*)&sB[buf_][(w * 4 + it_) * 512], \
                16, 0, 0);                                                        \
        }                                                                         \
    } while (0)

#define COMPUTE(buf_)                                                             \
    do {                                                                          \
        __builtin_amdgcn_s_setprio(1);                                            \
        _Pragma("unroll")                                                         \
        for (int ks_ = 0; ks_ < 4; ++ks_) {                                       \
            bf16x8 af[2], bfv[2];                                                 \
            _Pragma("unroll")                                                     \
            for (int mi_ = 0; mi_ < 2; ++mi_)                                     \
                af[mi_] = *(const bf16x8*)((const char*)&sA[buf_][0] +            \
                    baseA[mi_] + ((XA[mi_] ^ (ks_ << 1)) << 4));                  \
            _Pragma("unroll")                                                     \
            for (int ni_ = 0; ni_ < 2; ++ni_)                                     \
                bfv[ni_] = *(const bf16x8*)((const char*)&sB[buf_][0] +           \
                    baseB[ni_] + ((XB[ni_] ^ (ks_ << 1)) << 4));                  \
            _Pragma("unroll")                                                     \
            for (int mi_ = 0; mi_ < 2; ++mi_)                                     \
                _Pragma("unroll")                                                 \
                for (int ni_ = 0; ni_ < 2; ++ni_)                                 \
                    acc[mi_][ni_] = __builtin_amdgcn_mfma_f32_32x32x16_bf16(      \
                        af[mi_], bfv[ni_], acc[mi_][ni_], 0, 0, 0);               \
        }                                                                         \
        __builtin_amdgcn_s_setprio(0);                                            \
    } while (0)

// Store one 16-value chunk (mi,ni) of outB for the tile whose row base is base_.
#define STORE_CHUNK(c_, base_)                                                    \
    do {                                                                          \
        const int mi_ = (c_) >> 1, ni_ = (c_) & 1;                                \
        const int prow_ = (base_) + wr * 64 + mi_ * 32 + 4 * hi;                  \
        const int pcol_ = col0 + wc * 64 + ni_ * 32 + lr;                         \
        _Pragma("unroll")                                                         \
        for (int tt_ = 0; tt_ < 16; ++tt_) {                                      \
            const int q_ = tt_ & 3, p_ = tt_ >> 2;                                \
            out[(size_t)(prow_ + 8 * p_ + q_) * 8192 + pcol_] = outB[c_][tt_];    \
        }                                                                         \
    } while (0)

__global__ __launch_bounds__(256, 2) void gemm_kernel(
        const unsigned short* __restrict__ aB,
        const unsigned short* __restrict__ bB,
        const float* __restrict__ na,
        const float* __restrict__ nb,
        float* __restrict__ out) {
    __shared__ unsigned short sA[2][8192];
    __shared__ unsigned short sB[2][8192];
    __shared__ float sNA[1024];      // 8 tiles x 128 row-norms

    const int t = threadIdx.x;
    const int w = t >> 6, l = t & 63;
    const int wr = w >> 1, wc = w & 1;
    const int hi = l >> 5, lr = l & 31;

    const int bx = (int)blockIdx.x & 63;
    const int bb = (int)blockIdx.x >> 6;
    const int col0 = bx * BN;

    // staging source pre-swizzle (constant per thread)
    int rowIt[4], colIt[4];
#pragma unroll
    for (int it = 0; it < 4; ++it) {
        int G = (w * 4 + it) * 64 + l;
        int rp = G >> 4, pos = G & 15;
        int c2 = pos ^ (rp & 15);
        rowIt[it] = 2 * rp + (c2 >> 3);
        colIt[it] = (c2 & 7) * 8;          // ushort offset
    }
    // fragment read bases (byte offsets within 16KB buffer)
    int baseA[2], XA[2], baseB[2], XB[2];
#pragma unroll
    for (int mi = 0; mi < 2; ++mi) {
        int r = wr * 64 + mi * 32 + lr;
        baseA[mi] = (r >> 1) * 256;
        XA[mi] = (((r & 1) * 8) | hi) ^ ((r >> 1) & 15);
        int rb = wc * 64 + mi * 32 + lr;
        baseB[mi] = (rb >> 1) * 256;
        XB[mi] = (((rb & 1) * 8) | hi) ^ ((rb >> 1) & 15);
    }

    float nbv[2];
#pragma unroll
    for (int ni = 0; ni < 2; ++ni) nbv[ni] = nb[col0 + wc * 64 + ni * 32 + lr];

    float outB[4][16];
#pragma unroll
    for (int c = 0; c < 4; ++c)
#pragma unroll
        for (int tt = 0; tt < 16; ++tt) outB[c][tt] = 0.0f;

    // prologue: gather na slices (one f32x4 per thread), stage tile0 k0,k1
    const f32x4 naIn = *(const f32x4*)&na[(bb + (t >> 5) * 8) * 128 + (t & 31) * 4];
    {
        const int r0 = bb * BM;
        STAGE(r0, 0, 0);
        STAGE(r0, 1, 1);
    }
    *(f32x4*)&sNA[(t >> 5) * 128 + (t & 31) * 4] = naIn;
    asm volatile("s_waitcnt lgkmcnt(0)" ::: "memory");
    MEMFENCE;

    // Flattened rep*tile loop. Uniform schedule: every tile stages the NEXT
    // tile's k0/k1 (wrapping) and stores the PREVIOUS tile's outB (wrapping;
    // the rep-0/tile-0 "previous" store writes zeros that later reps and the
    // final flush overwrite with identical correct values).  Steady WAITV(40).
    for (int it2 = 0; it2 < 8 * REP; ++it2) {
        const int ti = it2 & 7;
        const int row0 = (bb + ti * 8) * BM;
        const int rowN = (bb + ((ti + 1) & 7) * 8) * BM;
        const int rowP = (bb + ((ti + 7) & 7) * 8) * BM;

        f32x16 acc[2][2];
#pragma unroll
        for (int mi = 0; mi < 2; ++mi)
#pragma unroll
            for (int ni = 0; ni < 2; ++ni) acc[mi][ni] = (f32x16)0.0f;

        // ---- P0: compute k0 (buf0, staged at prev tile's P2) ----
        if (it2 == 0) { WAITV(8); } else { WAITV(40); }
        BAR; MEMFENCE;
        COMPUTE(0);
        MEMFENCE; BAR; MEMFENCE;
        STAGE(row0, 2, 0);
        MEMFENCE;
        STORE_CHUNK(0, rowP);
        MEMFENCE;

        // ---- P1: compute k1 (buf1, staged at prev tile's P3) ----
        if (it2 == 0) { WAITV(24); } else { WAITV(40); }
        BAR; MEMFENCE;
        COMPUTE(1);
        MEMFENCE; BAR; MEMFENCE;
        STAGE(row0, 3, 1);
        MEMFENCE;
        STORE_CHUNK(1, rowP);
        MEMFENCE;

        // ---- P2: compute k2 (buf0, staged at P0) ----
        WAITV(40);
        BAR; MEMFENCE;
        COMPUTE(0);
        MEMFENCE; BAR; MEMFENCE;
        STAGE(rowN, 0, 0);
        MEMFENCE;
        STORE_CHUNK(2, rowP);
        MEMFENCE;

        // ---- P3: compute k3 (buf1, staged at P1) ----
        WAITV(40);
        BAR; MEMFENCE;
        COMPUTE(1);
        MEMFENCE; BAR; MEMFENCE;
        STAGE(rowN, 1, 1);
        MEMFENCE;
        STORE_CHUNK(3, rowP);
        MEMFENCE;

        // ---- E: epilogue into outB (no global stores here) ----
#pragma unroll
        for (int mi = 0; mi < 2; ++mi)
#pragma unroll
            for (int ni = 0; ni < 2; ++ni)
#pragma unroll
                for (int p = 0; p < 4; ++p) {
                    const f32x4 nv = *(const f32x4*)&sNA[ti * 128 + wr * 64 + mi * 32 + 8 * p + 4 * hi];
#pragma unroll
                    for (int q = 0; q < 4; ++q) {
                        const float dot = acc[mi][ni][p * 4 + q];
                        const float sq = nv[q] + nbv[ni] - 2.0f * dot;
                        outB[mi * 2 + ni][p * 4 + q] = 0.5f * __expf(-sq) + 0.5f * dot;
                    }
                }
        MEMFENCE;
    }

    // final flush: last tile (ti=7) chunks
    {
        const int base = (bb + 56) * BM;
#pragma unroll
        for (int c = 0; c < 4; ++c) STORE_CHUNK(c, base);
    }
}

// Fallback if workspace is too small: fully naive f32 (correct, slow).
__global__ void naive_kernel(const float* __restrict__ a,
                             const float* __restrict__ b,
                             float* __restrict__ out) {
    const size_t idx = (size_t)blockIdx.x * 256 + threadIdx.x;
    const int i = (int)(idx >> 13);
    const int j = (int)(idx & 8191);
    float dot = 0.f, naa = 0.f, nbb = 0.f;
    for (int k = 0; k < DIM; ++k) {
        const float x = a[(size_t)i * DIM + k];
        const float y = b[(size_t)j * DIM + k];
        dot += x * y; naa += x * x; nbb += y * y;
    }
    const float sq = naa + nbb - 2.0f * dot;
    out[idx] = 0.5f * __expf(-sq) + 0.5f * dot;
}

extern "C" void kernel_launch(void* const* d_in, const int* in_sizes, int n_in,
                              void* d_out, int out_size, void* d_ws, size_t ws_size,
                              hipStream_t stream) {
    const float* a = (const float*)d_in[0];
    const float* b = (const float*)d_in[1];
    // d_in[2]=Wq, d_in[3]=Wk unused: softmax over a 1x1 score == 1 exactly,
    // so attn_sim == a.b and the projections cancel.
    float* out = (float*)d_out;

    const size_t bf_bytes = (size_t)NR * DIM * sizeof(unsigned short);
    const size_t nrm_bytes = (size_t)NR * sizeof(float);
    const size_t need = 2 * bf_bytes + 2 * nrm_bytes;

    if (ws_size >= need) {
        unsigned short* aBf = (unsigned short*)d_ws;
        unsigned short* bBf = (unsigned short*)((char*)d_ws + bf_bytes);
        float* na = (float*)((char*)d_ws + 2 * bf_bytes);
        float* nb = (float*)((char*)d_ws + 2 * bf_bytes + nrm_bytes);

        prep_kernel<<<4096, 256, 0, stream>>>(a, b, aBf, bBf, na, nb);
        gemm_kernel<<<GRID, 256, 0, stream>>>(aBf, bBf, na, nb, out);
    } else {
        naive_kernel<<<((size_t)NR * NR) / 256, 256, 0, stream>>>(a, b, out);
    }
}

// Round 7
// 87.175 us; speedup vs baseline: 2.6687x; 2.6687x over previous
//
#include <hip/hip_runtime.h>
#include <stdint.h>

#define DIM 256
#define NR 8192
#define BM 128
#define BN 128
#define BK 32
#define GRID 4096       // one 128x128 tile per block

typedef __bf16 bf16x8 __attribute__((ext_vector_type(8)));
typedef float  f32x16 __attribute__((ext_vector_type(16)));
typedef float  f32x4  __attribute__((ext_vector_type(4)));

#define MEMFENCE asm volatile("" ::: "memory")
#define WAITV(N) asm volatile("s_waitcnt vmcnt(" #N ")" ::: "memory")
#define BAR __builtin_amdgcn_s_barrier()

__device__ __forceinline__ unsigned short f2bf_rne(float f) {
    unsigned int u = __float_as_uint(f);
    u += 0x7FFFu + ((u >> 16) & 1u);
    return (unsigned short)(u >> 16);
}

// One wave per row: f32 row -> bf16 + ||row||^2. Blocks [0,2048)->a, rest->b.
__global__ void prep_kernel(const float* __restrict__ a,
                            const float* __restrict__ b,
                            unsigned short* __restrict__ aB,
                            unsigned short* __restrict__ bB,
                            float* __restrict__ na,
                            float* __restrict__ nb) {
    const int w = threadIdx.x >> 6;
    const int l = threadIdx.x & 63;
    const int blk = blockIdx.x;
    const float* src; unsigned short* dst; float* nrm; int row;
    if (blk < 2048) { src = a; dst = aB; nrm = na; row = blk * 4 + w; }
    else            { src = b; dst = bB; nrm = nb; row = (blk - 2048) * 4 + w; }
    const float4 v = reinterpret_cast<const float4*>(src + (size_t)row * DIM)[l];
    float ss = v.x * v.x + v.y * v.y + v.z * v.z + v.w * v.w;
#pragma unroll
    for (int off = 32; off > 0; off >>= 1) ss += __shfl_down(ss, off);
    if (l == 0) nrm[row] = ss;
    ushort4 o = make_ushort4(f2bf_rne(v.x), f2bf_rne(v.y), f2bf_rne(v.z), f2bf_rne(v.w));
    reinterpret_cast<ushort4*>(dst + (size_t)row * DIM)[l] = o;
}

// LDS layout (per 8KB buffer, 16B granules): granule G holds global (r,c):
//   r = G>>2,  c = (G&3) ^ ((G>>3)&3)       [c = 16B chunk within 64B row]
// Read inverse: (r,c) lives at byte r*64 + ((c ^ ((r>>1)&3))<<4).
// 8 consecutive rows hit 8 distinct 128B-line positions -> conflict-free b128.
#define STAGE(kt_, buf_)                                                          \
    do {                                                                          \
        _Pragma("unroll")                                                         \
        for (int it_ = 0; it_ < 2; ++it_) {                                       \
            __builtin_amdgcn_global_load_lds(                                     \
                (const __attribute__((address_space(1))) void*)(aB +              \
                    (size_t)(row0 + w * 32 + it_ * 16 + rQ) * DIM + (kt_) * BK + cOf), \
                (__attribute__((address_space(3))) void*)&sA[buf_][(w * 2 + it_) * 512], \
                16, 0, 0);                                                        \
        }                                                                         \
        _Pragma("unroll")                                                         \
        for (int it_ = 0; it_ < 2; ++it_) {                                       \
            __builtin_amdgcn_global_load_lds(                                     \
                (const __attribute__((address_space(1))) void*)(bB +              \
                    (size_t)(col0 + w * 32 + it_ * 16 + rQ) * DIM + (kt_) * BK + cOf), \
                (__attribute__((address_space(3))) void*)&sB[buf_][(w * 2 + it_) * 512], \
                16, 0, 0);                                                        \
        }                                                                         \
    } while (0)

#define COMPUTE(buf_)                                                             \
    do {                                                                          \
        __builtin_amdgcn_s_setprio(1);                                            \
        _Pragma("unroll")                                                         \
        for (int ks_ = 0; ks_ < 2; ++ks_) {                                       \
            bf16x8 af[2], bfv[2];                                                 \
            _Pragma("unroll")                                                     \
            for (int mi_ = 0; mi_ < 2; ++mi_)                                     \
                af[mi_] = *(const bf16x8*)((const char*)&sA[buf_][0] +            \
                    baseA[mi_] + (((ks_ << 1) ^ XA[mi_]) << 4));                  \
            _Pragma("unroll")                                                     \
            for (int ni_ = 0; ni_ < 2; ++ni_)                                     \
                bfv[ni_] = *(const bf16x8*)((const char*)&sB[buf_][0] +           \
                    baseB[ni_] + (((ks_ << 1) ^ XB[ni_]) << 4));                  \
            _Pragma("unroll")                                                     \
            for (int mi_ = 0; mi_ < 2; ++mi_)                                     \
                _Pragma("unroll")                                                 \
                for (int ni_ = 0; ni_ < 2; ++ni_)                                 \
                    acc[mi_][ni_] = __builtin_amdgcn_mfma_f32_32x32x16_bf16(      \
                        af[mi_], bfv[ni_], acc[mi_][ni_], 0, 0, 0);               \
        }                                                                         \
        __builtin_amdgcn_s_setprio(0);                                            \
    } while (0)

__global__ __launch_bounds__(256, 4) void gemm_kernel(
        const unsigned short* __restrict__ aB,
        const unsigned short* __restrict__ bB,
        const float* __restrict__ na,
        const float* __restrict__ nb,
        float* __restrict__ out) {
    __shared__ unsigned short sA[2][4096];   // 2 x 8KB  (128 rows x 32)
    __shared__ unsigned short sB[2][4096];
    __shared__ float sNA[128];
    __shared__ float sNB[128];

    const int t = threadIdx.x;
    const int w = t >> 6, l = t & 63;
    const int wr = w >> 1, wc = w & 1;
    const int hi = l >> 5, lr = l & 31;

    const int bx = (int)blockIdx.x & 63;
    const int by = (int)blockIdx.x >> 6;
    const int col0 = bx * BN;
    const int row0 = by * BM;

    // staging source pre-swizzle (constant per thread)
    const int rQ = l >> 2;                          // row within 16-row region
    const int cOf = ((l & 3) ^ ((l >> 3) & 3)) * 8; // ushort offset in row

    // fragment read bases (byte offsets within 8KB buffer)
    int baseA[2], XA[2], baseB[2], XB[2];
#pragma unroll
    for (int mi = 0; mi < 2; ++mi) {
        const int r = wr * 64 + mi * 32 + lr;
        baseA[mi] = r * 64;
        XA[mi] = hi ^ ((r >> 1) & 3);
        const int rb = wc * 64 + mi * 32 + lr;
        baseB[mi] = rb * 64;
        XB[mi] = hi ^ ((rb >> 1) & 3);
    }

    // prologue: na/nb slices (wave 0 only) + stage k0,k1
    f32x4 nIn;
    if (t < 32)      nIn = *(const f32x4*)&na[row0 + t * 4];
    else if (t < 64) nIn = *(const f32x4*)&nb[col0 + (t - 32) * 4];
    STAGE(0, 0);
    STAGE(1, 1);
    if (t < 32)      *(f32x4*)&sNA[t * 4] = nIn;          // compiler waits the load
    else if (t < 64) *(f32x4*)&sNB[(t - 32) * 4] = nIn;
    asm volatile("s_waitcnt lgkmcnt(0)" ::: "memory");
    MEMFENCE;

    f32x16 acc[2][2];
#pragma unroll
    for (int mi = 0; mi < 2; ++mi)
#pragma unroll
        for (int ni = 0; ni < 2; ++ni) acc[mi][ni] = (f32x16)0.0f;

    // 8 k-phases; stores only at E => WAITV never gates a store.
#pragma unroll
    for (int p = 0; p < 8; ++p) {
        if (p == 7) { WAITV(0); } else { WAITV(4); }
        BAR; MEMFENCE;
        COMPUTE(p & 1);
        MEMFENCE;
        if (p < 6) {
            BAR; MEMFENCE;
            STAGE(p + 2, p & 1);
            MEMFENCE;
        }
    }

    // ---- E: epilogue + 4x4 lane transpose + dwordx4 stores ----
    const int m4 = l & 3;
    const int colT = col0 + wc * 64 + (lr >> 2) * 4;
#pragma unroll
    for (int ni = 0; ni < 2; ++ni) {
        const float nbv = sNB[wc * 64 + ni * 32 + lr];
#pragma unroll
        for (int mi = 0; mi < 2; ++mi) {
#pragma unroll
            for (int p = 0; p < 4; ++p) {
                const f32x4 nv = *(const f32x4*)&sNA[wr * 64 + mi * 32 + 8 * p + 4 * hi];
                float av[4];
#pragma unroll
                for (int q = 0; q < 4; ++q) {
                    const float dot = acc[mi][ni][p * 4 + q];
                    const float sq = nv[q] + nbv - 2.0f * dot;
                    av[q] = 0.5f * __expf(-sq) + 0.5f * dot;
                }
                // 4x4 transpose within 4-lane groups (2 butterfly rounds)
                float tv;
                tv = __shfl_xor((m4 & 1) ? av[0] : av[1], 1);
                if (m4 & 1) av[0] = tv; else av[1] = tv;
                tv = __shfl_xor((m4 & 1) ? av[2] : av[3], 1);
                if (m4 & 1) av[2] = tv; else av[3] = tv;
                tv = __shfl_xor((m4 & 2) ? av[0] : av[2], 2);
                if (m4 & 2) av[0] = tv; else av[2] = tv;
                tv = __shfl_xor((m4 & 2) ? av[1] : av[3], 2);
                if (m4 & 2) av[1] = tv; else av[3] = tv;
                // lane holds row (..+m4), 4 consecutive cols -> one dwordx4
                const int row = row0 + wr * 64 + mi * 32 + 8 * p + 4 * hi + m4;
                f32x4 st; st[0] = av[0]; st[1] = av[1]; st[2] = av[2]; st[3] = av[3];
                *(f32x4*)&out[(size_t)row * 8192 + colT + ni * 32] = st;
            }
        }
    }
}

// Fallback if workspace is too small: fully naive f32 (correct, slow).
__global__ void naive_kernel(const float* __restrict__ a,
                             const float* __restrict__ b,
                             float* __restrict__ out) {
    const size_t idx = (size_t)blockIdx.x * 256 + threadIdx.x;
    const int i = (int)(idx >> 13);
    const int j = (int)(idx & 8191);
    float dot = 0.f, naa = 0.f, nbb = 0.f;
    for (int k = 0; k < DIM; ++k) {
        const float x = a[(size_t)i * DIM + k];
        const float y = b[(size_t)j * DIM + k];
        dot += x * y; naa += x * x; nbb += y * y;
    }
    const float sq = naa + nbb - 2.0f * dot;
    out[idx] = 0.5f * __expf(-sq) + 0.5f * dot;
}

extern "C" void kernel_launch(void* const* d_in, const int* in_sizes, int n_in,
                              void* d_out, int out_size, void* d_ws, size_t ws_size,
                              hipStream_t stream) {
    const float* a = (const float*)d_in[0];
    const float* b = (const float*)d_in[1];
    // d_in[2]=Wq, d_in[3]=Wk unused: softmax over a 1x1 score == 1 exactly,
    // so attn_sim == a.b and the projections cancel.
    float* out = (float*)d_out;

    const size_t bf_bytes = (size_t)NR * DIM * sizeof(unsigned short);
    const size_t nrm_bytes = (size_t)NR * sizeof(float);
    const size_t need = 2 * bf_bytes + 2 * nrm_bytes;

    if (ws_size >= need) {
        unsigned short* aBf = (unsigned short*)d_ws;
        unsigned short* bBf = (unsigned short*)((char*)d_ws + bf_bytes);
        float* na = (float*)((char*)d_ws + 2 * bf_bytes);
        float* nb = (float*)((char*)d_ws + 2 * bf_bytes + nrm_bytes);

        prep_kernel<<<4096, 256, 0, stream>>>(a, b, aBf, bBf, na, nb);
        gemm_kernel<<<GRID, 256, 0, stream>>>(aBf, bBf, na, nb, out);
    } else {
        naive_kernel<<<((size_t)NR * NR) / 256, 256, 0, stream>>>(a, b, out);
    }
}